// Round 3
// baseline (433.963 us; speedup 1.0000x reference)
//
#include <hip/hip_runtime.h>
#include <hip/hip_bf16.h>

typedef __hip_bfloat16 bf16;

#define ED 768
#define NB 8
#define BS 96
#define NH 12
#define HD 64
#define SEQ 2048
#define NBATCH 4
#define NROWS (NBATCH*SEQ)
#define RPB 4   // rows per workgroup in urdhva kernels

__device__ __forceinline__ float b2f(bf16 v){ return __bfloat162float(v); }
__device__ __forceinline__ bf16 f2b(float v){ return __float2bfloat16(v); }

// ---------------------------------------------------------------------------
// Fused q/k/v urdhva linear: y[n,b,t] = sum_s x[n,b,s]*Wv[b,s,t]
//                                     + (b>0)   sum_s x[n,b-1,s]*Wr[b-1,s,t]
//                                     + (b<7)   sum_s x[n,b+1,s]*Wl[b,s,t]  + bias
// One workgroup handles RPB=4 consecutive rows; x staged in LDS as fp32.
// Inputs f32; q/k/v written as bf16 (ws traffic/precision tradeoff: fp32 accum).
// ---------------------------------------------------------------------------
__global__ __launch_bounds__(256) void qkv_urdhva(
    const float* __restrict__ x,
    const float* __restrict__ qWv, const float* __restrict__ qWr, const float* __restrict__ qWl, const float* __restrict__ qb,
    const float* __restrict__ kWv, const float* __restrict__ kWr, const float* __restrict__ kWl, const float* __restrict__ kb,
    const float* __restrict__ vWv, const float* __restrict__ vWr, const float* __restrict__ vWl, const float* __restrict__ vb,
    bf16* __restrict__ q, bf16* __restrict__ k, bf16* __restrict__ v)
{
    __shared__ float xs[RPB][ED];
    const int n0 = blockIdx.x * RPB;
    const int tid = threadIdx.x;

    // stage 4 rows of x (contiguous, f32) into LDS via float4
    {
        const float4* src = (const float4*)(x + (size_t)n0*ED);
        float4* dst = (float4*)(&xs[0][0]);
        for (int i = tid; i < RPB*ED/4; i += 256) dst[i] = src[i];
    }
    __syncthreads();

    for (int o = tid; o < ED; o += 256) {
        const int b = o / BS;
        const int t = o - b*BS;

        float aq[RPB], ak[RPB], av[RPB];
        const float bq = qb[o], bk = kb[o], bv = vb[o];
        #pragma unroll
        for (int r = 0; r < RPB; ++r) { aq[r] = bq; ak[r] = bk; av[r] = bv; }

        auto contrib = [&](int sb, const float* wq, const float* wk, const float* wv) {
            #pragma unroll 8
            for (int s = 0; s < BS; ++s) {
                const float wqv = wq[s*BS];
                const float wkv = wk[s*BS];
                const float wvv = wv[s*BS];
                #pragma unroll
                for (int r = 0; r < RPB; ++r) {
                    const float xv = xs[r][sb*BS + s];
                    aq[r] += xv * wqv;
                    ak[r] += xv * wkv;
                    av[r] += xv * wvv;
                }
            }
        };

        contrib(b,   qWv + b*BS*BS + t,     kWv + b*BS*BS + t,     vWv + b*BS*BS + t);
        if (b > 0)
            contrib(b-1, qWr + (b-1)*BS*BS + t, kWr + (b-1)*BS*BS + t, vWr + (b-1)*BS*BS + t);
        if (b < NB-1)
            contrib(b+1, qWl + b*BS*BS + t,     kWl + b*BS*BS + t,     vWl + b*BS*BS + t);

        #pragma unroll
        for (int r = 0; r < RPB; ++r) {
            q[(size_t)(n0+r)*ED + o] = f2b(aq[r]);
            k[(size_t)(n0+r)*ED + o] = f2b(ak[r]);
            v[(size_t)(n0+r)*ED + o] = f2b(av[r]);
        }
    }
}

// ---------------------------------------------------------------------------
// Sparse attention. Mask (structural): row i attends to j in [i-4, i] and
// j = i - 8*2^k for k >= 0 (j >= 0).  <= 13 keys per row.
// One wave per (batch, head, query). lane = slot (0..15) x dseg (0..3):
// 4 lanes cooperate on each 64-wide q.k dot.
// ---------------------------------------------------------------------------
__global__ __launch_bounds__(256) void sparse_attn(
    const bf16* __restrict__ q, const bf16* __restrict__ k, const bf16* __restrict__ v,
    float* __restrict__ out)
{
    const int tid  = threadIdx.x;
    const int lane = tid & 63;
    const int wid  = tid >> 6;
    const int g = blockIdx.x * 4 + wid;      // query id in [0, NBATCH*NH*SEQ)
    const int i  = g & (SEQ-1);
    const int hh = (g >> 11) % NH;
    const int bb = g / (SEQ*NH);

    const int slot = lane & 15;
    const int dseg = lane >> 4;

    int j;
    if (slot < 5)       j = i - 4 + slot;
    else if (slot < 13) j = i - (8 << (slot - 5));
    else                j = -1;
    const bool valid = (j >= 0);

    const bf16* qrow = q + ((size_t)bb*SEQ + i)*ED + hh*HD;

    float s = 0.f;
    if (valid) {
        const bf16* krow = k + ((size_t)bb*SEQ + j)*ED + hh*HD;
        const int d0 = dseg * 16;
        #pragma unroll
        for (int t = 0; t < 16; ++t)
            s += b2f(qrow[d0 + t]) * b2f(krow[d0 + t]);
    }
    // full dot: reduce over the 4 cooperating lanes (xor 16, 32)
    s += __shfl_xor(s, 16);
    s += __shfl_xor(s, 32);
    s = valid ? s * 0.125f : -1e30f;   // 1/sqrt(64)

    // softmax over the 16 slot lanes (slots 13..15 are -1e30 -> contribute 0)
    float m = s;
    #pragma unroll
    for (int off = 1; off < 16; off <<= 1) m = fmaxf(m, __shfl_xor(m, off));
    float p = valid ? __expf(s - m) : 0.f;
    float denom = p;
    #pragma unroll
    for (int off = 1; off < 16; off <<= 1) denom += __shfl_xor(denom, off);
    p /= denom;

    // PV: each lane owns output dim d = lane
    float acc = 0.f;
    const bf16* vbase = v + (size_t)bb*SEQ*ED + hh*HD;
    #pragma unroll
    for (int sl = 0; sl < 13; ++sl) {
        const float ps = __shfl(p, sl);
        const int   js = __shfl(j, sl);
        if (js >= 0) acc += ps * b2f(vbase[(size_t)js*ED + lane]);
    }
    out[((size_t)bb*SEQ + i)*ED + hh*HD + lane] = acc;
}

// ---------------------------------------------------------------------------
// Output urdhva projection. Reads and writes d_out IN PLACE: each workgroup
// stages its own 4 rows into LDS before any write (race-free: no other
// workgroup touches these rows).
// ---------------------------------------------------------------------------
__global__ __launch_bounds__(256) void o_urdhva(
    float* __restrict__ io,
    const float* __restrict__ Wv, const float* __restrict__ Wr, const float* __restrict__ Wl,
    const float* __restrict__ bias)
{
    __shared__ float xs[RPB][ED];
    const int n0 = blockIdx.x * RPB;
    const int tid = threadIdx.x;

    {
        const float4* src = (const float4*)(io + (size_t)n0*ED);
        float4* dst = (float4*)(&xs[0][0]);
        for (int i = tid; i < RPB*ED/4; i += 256) dst[i] = src[i];
    }
    __syncthreads();

    for (int o = tid; o < ED; o += 256) {
        const int b = o / BS;
        const int t = o - b*BS;

        float acc[RPB];
        const float bi = bias[o];
        #pragma unroll
        for (int r = 0; r < RPB; ++r) acc[r] = bi;

        auto contrib = [&](int sb, const float* w) {
            #pragma unroll 8
            for (int s = 0; s < BS; ++s) {
                const float wv = w[s*BS];
                #pragma unroll
                for (int r = 0; r < RPB; ++r)
                    acc[r] += xs[r][sb*BS + s] * wv;
            }
        };

        contrib(b, Wv + b*BS*BS + t);
        if (b > 0)     contrib(b-1, Wr + (b-1)*BS*BS + t);
        if (b < NB-1)  contrib(b+1, Wl + b*BS*BS + t);

        #pragma unroll
        for (int r = 0; r < RPB; ++r)
            io[(size_t)(n0+r)*ED + o] = acc[r];
    }
}

// ---------------------------------------------------------------------------
extern "C" void kernel_launch(void* const* d_in, const int* in_sizes, int n_in,
                              void* d_out, int out_size, void* d_ws, size_t ws_size,
                              hipStream_t stream) {
    const float* x   = (const float*)d_in[0];
    const float* qWv = (const float*)d_in[1];
    const float* qWr = (const float*)d_in[2];
    const float* qWl = (const float*)d_in[3];
    const float* qb  = (const float*)d_in[4];
    const float* kWv = (const float*)d_in[5];
    const float* kWr = (const float*)d_in[6];
    const float* kWl = (const float*)d_in[7];
    const float* kb  = (const float*)d_in[8];
    const float* vWv = (const float*)d_in[9];
    const float* vWr = (const float*)d_in[10];
    const float* vWl = (const float*)d_in[11];
    const float* vb  = (const float*)d_in[12];
    const float* oWv = (const float*)d_in[13];
    const float* oWr = (const float*)d_in[14];
    const float* oWl = (const float*)d_in[15];
    const float* ob  = (const float*)d_in[16];
    // d_in[17] = sparse_mask: structural, computed analytically in-kernel.

    bf16* q = (bf16*)d_ws;
    bf16* k = q + (size_t)NROWS*ED;
    bf16* v = k + (size_t)NROWS*ED;
    float* ao = (float*)d_out;   // attention output lives in d_out, o-proj is in-place

    qkv_urdhva<<<NROWS/RPB, 256, 0, stream>>>(x,
        qWv,qWr,qWl,qb, kWv,kWr,kWl,kb, vWv,vWr,vWl,vb, q, k, v);

    sparse_attn<<<(NBATCH*NH*SEQ)/4, 256, 0, stream>>>(q, k, v, ao);

    o_urdhva<<<NROWS/RPB, 256, 0, stream>>>(ao, oWv, oWr, oWl, ob);
}

// Round 4
// 179.945 us; speedup vs baseline: 2.4116x; 2.4116x over previous
//
#include <hip/hip_runtime.h>
#include <hip/hip_bf16.h>

typedef __hip_bfloat16 bf16;
typedef __attribute__((ext_vector_type(8))) short short8;   // 8 bf16 in 4 VGPRs
typedef __attribute__((ext_vector_type(4))) float f32x4;

#define ED 768
#define NB 8
#define BS 96
#define NH 12
#define HD 64
#define SEQ 2048
#define NBATCH 4
#define NROWS (NBATCH*SEQ)   // 8192

__device__ __forceinline__ float b2f(bf16 v){ return __bfloat162float(v); }
__device__ __forceinline__ bf16 f2b(float v){ return __float2bfloat16(v); }
__device__ __forceinline__ short f2bs(float v){
    return (short)__builtin_bit_cast(unsigned short, __float2bfloat16(v));
}

// ---------------------------------------------------------------------------
// Densify one urdhva weight set into Wd[t][s] (768x768, bf16, TRANSPOSED so
// that the GEMM's B-fragment reads are contiguous-in-K per lane).
//   out-block bt gets: bs==bt -> Wv[bt], bs==bt-1 -> Wr[bt-1], bs==bt+1 -> Wl[bt]
// ---------------------------------------------------------------------------
__global__ __launch_bounds__(256) void densify(
    const float* __restrict__ Wv, const float* __restrict__ Wr,
    const float* __restrict__ Wl, bf16* __restrict__ Wd)
{
    const int idx = blockIdx.x*256 + threadIdx.x;   // over 768*768
    const int t = idx / ED, s = idx - t*ED;
    const int bt = t / BS, tt = t - bt*BS;
    const int bs = s / BS, ss = s - bs*BS;
    float val = 0.f;
    if (bs == bt)        val = Wv[(bt*BS + ss)*BS + tt];
    else if (bs == bt-1) val = Wr[((bt-1)*BS + ss)*BS + tt];
    else if (bs == bt+1) val = Wl[(bt*BS + ss)*BS + tt];
    Wd[idx] = f2b(val);
}

// ---------------------------------------------------------------------------
// Banded MFMA GEMM: Out[n][t] = sum_{s in band(bt)} A[n][s] * Wd[t][s] + bias[t]
// Grid: (NROWS/128, NB, Z). Block 256 = 4 waves; wave w owns rows
// [bx*128 + w*32, +32) x all 96 cols of out-block by. K-window = the band.
// No LDS: A and B fragments load straight from global (L2-resident).
// 16x16x32 bf16 MFMA; A lane layout row=l&15, k=(l>>4)*8+i (contiguous 16B);
// B lane layout col=l&15, k=(l>>4)*8+i; C/D row=(l>>4)*4+r, col=l&15 (m89).
// ---------------------------------------------------------------------------
template<bool ABF16, bool OBF16>
__global__ __launch_bounds__(256) void urdhva_gemm(
    const void* __restrict__ Ain,       // [NROWS][ED] f32 (ABF16=0) or bf16
    const bf16* __restrict__ WdBase,    // z-strided ED*ED
    const float* __restrict__ bias0, const float* __restrict__ bias1,
    const float* __restrict__ bias2,
    void* __restrict__ OutBase)         // z-strided NROWS*ED, bf16 or f32
{
    const int z = blockIdx.z;
    const bf16* Wd = WdBase + (size_t)z*ED*ED;
    const float* bias = (z==0) ? bias0 : (z==1) ? bias1 : bias2;

    const int lane = threadIdx.x & 63;
    const int wave = threadIdx.x >> 6;
    const int rowbase = blockIdx.x*128 + wave*32;
    const int ob = blockIdx.y;
    const int colbase = ob*BS;
    const int klo = (ob==0)    ? 0  : (ob-1)*BS;
    const int khi = (ob==NB-1) ? ED : (ob+2)*BS;

    const int l15 = lane & 15;
    const int lk8 = (lane >> 4) << 3;

    f32x4 acc[2][6];
    #pragma unroll
    for (int i=0;i<2;++i)
        #pragma unroll
        for (int j=0;j<6;++j) acc[i][j] = (f32x4){0.f,0.f,0.f,0.f};

    const size_t arow0 = (size_t)(rowbase + l15)*ED + lk8;
    const bf16* wbase  = Wd + (size_t)(colbase + l15)*ED + lk8;

    for (int k0 = klo; k0 < khi; k0 += 32) {
        short8 a[2], b[6];
        #pragma unroll
        for (int rf = 0; rf < 2; ++rf) {
            if (ABF16) {
                a[rf] = *(const short8*)((const bf16*)Ain + arow0 + (size_t)rf*16*ED + k0);
            } else {
                const float* p = (const float*)Ain + arow0 + (size_t)rf*16*ED + k0;
                const float4 x0 = *(const float4*)p;
                const float4 x1 = *(const float4*)(p+4);
                short8 tmp;
                tmp[0]=f2bs(x0.x); tmp[1]=f2bs(x0.y); tmp[2]=f2bs(x0.z); tmp[3]=f2bs(x0.w);
                tmp[4]=f2bs(x1.x); tmp[5]=f2bs(x1.y); tmp[6]=f2bs(x1.z); tmp[7]=f2bs(x1.w);
                a[rf] = tmp;
            }
        }
        #pragma unroll
        for (int nf = 0; nf < 6; ++nf)
            b[nf] = *(const short8*)(wbase + (size_t)nf*16*ED + k0);
        #pragma unroll
        for (int rf = 0; rf < 2; ++rf)
            #pragma unroll
            for (int nf = 0; nf < 6; ++nf)
                acc[rf][nf] = __builtin_amdgcn_mfma_f32_16x16x32_bf16(
                                  a[rf], b[nf], acc[rf][nf], 0, 0, 0);
    }

    const int rbase = (lane >> 4) * 4;
    #pragma unroll
    for (int rf = 0; rf < 2; ++rf) {
        #pragma unroll
        for (int nf = 0; nf < 6; ++nf) {
            const int col = colbase + nf*16 + l15;
            const float bv = bias[col];
            #pragma unroll
            for (int r = 0; r < 4; ++r) {
                const int row = rowbase + rf*16 + rbase + r;
                const float v = acc[rf][nf][r] + bv;
                if (OBF16)
                    ((bf16*)OutBase)[(size_t)z*NROWS*ED + (size_t)row*ED + col] = f2b(v);
                else
                    ((float*)OutBase)[(size_t)row*ED + col] = v;
            }
        }
    }
}

// ---------------------------------------------------------------------------
// Sparse attention. Mask (structural): row i attends to j in [i-4, i] and
// j = i - 8*2^k for k >= 0 (j >= 0).  <= 13 keys per row.
// One wave per (batch, head, query). lane = slot (0..15) x dseg (0..3).
// ---------------------------------------------------------------------------
__global__ __launch_bounds__(256) void sparse_attn(
    const bf16* __restrict__ q, const bf16* __restrict__ k, const bf16* __restrict__ v,
    bf16* __restrict__ out)
{
    const int tid  = threadIdx.x;
    const int lane = tid & 63;
    const int wid  = tid >> 6;
    const int g = blockIdx.x * 4 + wid;
    const int i  = g & (SEQ-1);
    const int hh = (g >> 11) % NH;
    const int bb = g / (SEQ*NH);

    const int slot = lane & 15;
    const int dseg = lane >> 4;

    int j;
    if (slot < 5)       j = i - 4 + slot;
    else if (slot < 13) j = i - (8 << (slot - 5));
    else                j = -1;
    const bool valid = (j >= 0);

    const bf16* qrow = q + ((size_t)bb*SEQ + i)*ED + hh*HD;

    float s = 0.f;
    if (valid) {
        const bf16* krow = k + ((size_t)bb*SEQ + j)*ED + hh*HD;
        const int d0 = dseg * 16;
        #pragma unroll
        for (int t = 0; t < 16; ++t)
            s += b2f(qrow[d0 + t]) * b2f(krow[d0 + t]);
    }
    s += __shfl_xor(s, 16);
    s += __shfl_xor(s, 32);
    s = valid ? s * 0.125f : -1e30f;   // 1/sqrt(64)

    float m = s;
    #pragma unroll
    for (int off = 1; off < 16; off <<= 1) m = fmaxf(m, __shfl_xor(m, off));
    float p = valid ? __expf(s - m) : 0.f;
    float denom = p;
    #pragma unroll
    for (int off = 1; off < 16; off <<= 1) denom += __shfl_xor(denom, off);
    p /= denom;

    float acc = 0.f;
    const bf16* vbase = v + (size_t)bb*SEQ*ED + hh*HD;
    #pragma unroll
    for (int sl = 0; sl < 13; ++sl) {
        const float ps = __shfl(p, sl);
        const int   js = __shfl(j, sl);
        if (js >= 0) acc += ps * b2f(vbase[(size_t)js*ED + lane]);
    }
    out[((size_t)bb*SEQ + i)*ED + hh*HD + lane] = f2b(acc);
}

// ---------------------------------------------------------------------------
extern "C" void kernel_launch(void* const* d_in, const int* in_sizes, int n_in,
                              void* d_out, int out_size, void* d_ws, size_t ws_size,
                              hipStream_t stream) {
    const float* x   = (const float*)d_in[0];
    const float* qWv = (const float*)d_in[1];
    const float* qWr = (const float*)d_in[2];
    const float* qWl = (const float*)d_in[3];
    const float* qb  = (const float*)d_in[4];
    const float* kWv = (const float*)d_in[5];
    const float* kWr = (const float*)d_in[6];
    const float* kWl = (const float*)d_in[7];
    const float* kb  = (const float*)d_in[8];
    const float* vWv = (const float*)d_in[9];
    const float* vWr = (const float*)d_in[10];
    const float* vWl = (const float*)d_in[11];
    const float* vb  = (const float*)d_in[12];
    const float* oWv = (const float*)d_in[13];
    const float* oWr = (const float*)d_in[14];
    const float* oWl = (const float*)d_in[15];
    const float* ob  = (const float*)d_in[16];
    // d_in[17] = sparse_mask: structural, computed analytically in-kernel.

    const size_t QKV = (size_t)NROWS*ED;   // 6.29M elems
    bf16* q   = (bf16*)d_ws;
    bf16* k   = q + QKV;
    bf16* v   = k + QKV;
    bf16* ao  = v + QKV;
    bf16* Wdq = ao + QKV;
    bf16* Wdk = Wdq + (size_t)ED*ED;
    bf16* Wdv = Wdk + (size_t)ED*ED;
    bf16* Wdo = Wdv + (size_t)ED*ED;
    // total ws use: 4*12.58MB + 4*1.18MB ~= 55 MB

    densify<<<ED*ED/256, 256, 0, stream>>>(qWv, qWr, qWl, Wdq);
    densify<<<ED*ED/256, 256, 0, stream>>>(kWv, kWr, kWl, Wdk);
    densify<<<ED*ED/256, 256, 0, stream>>>(vWv, vWr, vWl, Wdv);
    densify<<<ED*ED/256, 256, 0, stream>>>(oWv, oWr, oWl, Wdo);

    // fused q/k/v banded GEMM (z = which projection; Wd and out are z-strided)
    urdhva_gemm<false, true><<<dim3(NROWS/128, NB, 3), 256, 0, stream>>>(
        x, Wdq, qb, kb, vb, q);

    sparse_attn<<<(NBATCH*NH*SEQ)/4, 256, 0, stream>>>(q, k, v, ao);

    urdhva_gemm<true, false><<<dim3(NROWS/128, NB, 1), 256, 0, stream>>>(
        ao, Wdo, ob, ob, ob, d_out);
}

// Round 5
// 147.822 us; speedup vs baseline: 2.9357x; 1.2173x over previous
//
#include <hip/hip_runtime.h>
#include <hip/hip_bf16.h>

typedef __hip_bfloat16 bf16;
typedef __attribute__((ext_vector_type(8))) short short8;   // 8 bf16 in 4 VGPRs
typedef __attribute__((ext_vector_type(4))) float f32x4;

#define ED 768
#define NB 8
#define BS 96
#define NH 12
#define HD 64
#define SEQ 2048
#define NBATCH 4
#define NROWS (NBATCH*SEQ)   // 8192

__device__ __forceinline__ float b2f(bf16 v){ return __bfloat162float(v); }
__device__ __forceinline__ bf16 f2b(float v){ return __float2bfloat16(v); }
__device__ __forceinline__ short f2bs(float v){
    return (short)__builtin_bit_cast(unsigned short, __float2bfloat16(v));
}
__device__ __forceinline__ float bs2f(short u){
    return __builtin_bit_cast(float, ((unsigned)(unsigned short)u) << 16);
}

// ---------------------------------------------------------------------------
// One-time convert x (f32) -> bf16, so GEMM A-loads are short8 with no VALU cvt.
// ---------------------------------------------------------------------------
__global__ __launch_bounds__(256) void xcvt(
    const float* __restrict__ x, bf16* __restrict__ xb)
{
    const int idx = blockIdx.x*256 + threadIdx.x;     // one short8 per thread
    const float4 a = ((const float4*)x)[(size_t)idx*2];
    const float4 c = ((const float4*)x)[(size_t)idx*2 + 1];
    short8 o;
    o[0]=f2bs(a.x); o[1]=f2bs(a.y); o[2]=f2bs(a.z); o[3]=f2bs(a.w);
    o[4]=f2bs(c.x); o[5]=f2bs(c.y); o[6]=f2bs(c.z); o[7]=f2bs(c.w);
    ((short8*)xb)[idx] = o;
}

// ---------------------------------------------------------------------------
// Densify all 4 urdhva weight sets into Wd[z][t][s] (768x768 bf16, transposed
// so GEMM B-fragment reads are contiguous-in-K per lane). grid.y = z (q,k,v,o).
// ---------------------------------------------------------------------------
__global__ __launch_bounds__(256) void densify4(
    const float* __restrict__ qWv, const float* __restrict__ qWr, const float* __restrict__ qWl,
    const float* __restrict__ kWv, const float* __restrict__ kWr, const float* __restrict__ kWl,
    const float* __restrict__ vWv, const float* __restrict__ vWr, const float* __restrict__ vWl,
    const float* __restrict__ oWv, const float* __restrict__ oWr, const float* __restrict__ oWl,
    bf16* __restrict__ WdBase)
{
    const int z = blockIdx.y;
    const float* Wv = (z==0)?qWv:(z==1)?kWv:(z==2)?vWv:oWv;
    const float* Wr = (z==0)?qWr:(z==1)?kWr:(z==2)?vWr:oWr;
    const float* Wl = (z==0)?qWl:(z==1)?kWl:(z==2)?vWl:oWl;
    bf16* Wd = WdBase + (size_t)z*ED*ED;

    const int idx = blockIdx.x*256 + threadIdx.x;   // over 768*768
    const int t = idx / ED, s = idx - t*ED;
    const int bt = t / BS, tt = t - bt*BS;
    const int bs = s / BS, ss = s - bs*BS;
    float val = 0.f;
    if (bs == bt)        val = Wv[(bt*BS + ss)*BS + tt];
    else if (bs == bt-1) val = Wr[((bt-1)*BS + ss)*BS + tt];
    else if (bs == bt+1) val = Wl[(bt*BS + ss)*BS + tt];
    Wd[idx] = f2b(val);
}

// ---------------------------------------------------------------------------
// Banded MFMA GEMM: Out[n][t] = sum_{s in band(bt)} A[n][s]*Wd[t][s] + bias[t]
// Grid: (NROWS/(RF*64), NB, Z). Block 256 = 4 waves; wave owns RF*16 rows x
// 96 cols of out-block by. A,B fragments load straight from global (L2-hot).
// 16x16x32 bf16 MFMA; C/D layout row=(l>>4)*4+r, col=l&15 (m89).
// ---------------------------------------------------------------------------
template<int RF, bool OBF16>
__global__ __launch_bounds__(256) void urdhva_gemm(
    const bf16* __restrict__ A,         // [NROWS][ED] bf16
    const bf16* __restrict__ WdBase,    // z-strided ED*ED
    const float* __restrict__ bias0, const float* __restrict__ bias1,
    const float* __restrict__ bias2,
    void* __restrict__ OutBase)         // z-strided NROWS*ED, bf16 or f32
{
    const int z = blockIdx.z;
    const bf16* Wd = WdBase + (size_t)z*ED*ED;
    const float* bias = (z==0) ? bias0 : (z==1) ? bias1 : bias2;

    const int lane = threadIdx.x & 63;
    const int wave = threadIdx.x >> 6;
    const int rowbase = blockIdx.x*(RF*64) + wave*(RF*16);
    const int ob = blockIdx.y;
    const int colbase = ob*BS;
    const int klo = (ob==0)    ? 0  : (ob-1)*BS;
    const int khi = (ob==NB-1) ? ED : (ob+2)*BS;

    const int l15 = lane & 15;
    const int lk8 = (lane >> 4) << 3;

    f32x4 acc[RF][6];
    #pragma unroll
    for (int i=0;i<RF;++i)
        #pragma unroll
        for (int j=0;j<6;++j) acc[i][j] = (f32x4){0.f,0.f,0.f,0.f};

    const bf16* abase = A  + (size_t)(rowbase + l15)*ED + lk8;
    const bf16* wbase = Wd + (size_t)(colbase + l15)*ED + lk8;

    for (int k0 = klo; k0 < khi; k0 += 32) {
        short8 a[RF], b[6];
        #pragma unroll
        for (int rf = 0; rf < RF; ++rf)
            a[rf] = *(const short8*)(abase + (size_t)rf*16*ED + k0);
        #pragma unroll
        for (int nf = 0; nf < 6; ++nf)
            b[nf] = *(const short8*)(wbase + (size_t)nf*16*ED + k0);
        #pragma unroll
        for (int rf = 0; rf < RF; ++rf)
            #pragma unroll
            for (int nf = 0; nf < 6; ++nf)
                acc[rf][nf] = __builtin_amdgcn_mfma_f32_16x16x32_bf16(
                                  a[rf], b[nf], acc[rf][nf], 0, 0, 0);
    }

    const int rbase = (lane >> 4) * 4;
    #pragma unroll
    for (int rf = 0; rf < RF; ++rf) {
        #pragma unroll
        for (int nf = 0; nf < 6; ++nf) {
            const int col = colbase + nf*16 + l15;
            const float bv = bias[col];
            #pragma unroll
            for (int r = 0; r < 4; ++r) {
                const int row = rowbase + rf*16 + rbase + r;
                const float vv = acc[rf][nf][r] + bv;
                if (OBF16)
                    ((bf16*)OutBase)[(size_t)z*NROWS*ED + (size_t)row*ED + col] = f2b(vv);
                else
                    ((float*)OutBase)[(size_t)row*ED + col] = vv;
            }
        }
    }
}

// ---------------------------------------------------------------------------
// Sparse attention. Mask (structural): row i attends to j in [i-4, i] and
// j = i - 8*2^m for m >= 0 (j >= 0).  <= 13 keys per row.
// One wave per (batch, head, query). lane = slot (0..15) x dseg (0..3).
// Vector q/k loads; PV broadcast via readlane (SGPR p/j, scalar branch).
// ---------------------------------------------------------------------------
__global__ __launch_bounds__(256) void sparse_attn(
    const bf16* __restrict__ q, const bf16* __restrict__ k, const bf16* __restrict__ v,
    bf16* __restrict__ out)
{
    const int tid  = threadIdx.x;
    const int lane = tid & 63;
    const int wid  = tid >> 6;
    const int g = blockIdx.x * 4 + wid;
    const int i  = g & (SEQ-1);
    const int hh = (g >> 11) % NH;
    const int bb = g / (SEQ*NH);

    const int slot = lane & 15;
    const int dseg = lane >> 4;

    int j;
    if (slot < 5)       j = i - 4 + slot;
    else if (slot < 13) j = i - (8 << (slot - 5));
    else                j = -1;
    const bool valid = (j >= 0);

    const bf16* qrow = q + ((size_t)bb*SEQ + i)*ED + hh*HD + dseg*16;
    const short8 q0 = *(const short8*)qrow;
    const short8 q1 = *(const short8*)(qrow + 8);

    float s = 0.f;
    if (valid) {
        const bf16* krow = k + ((size_t)bb*SEQ + j)*ED + hh*HD + dseg*16;
        const short8 k0 = *(const short8*)krow;
        const short8 k1 = *(const short8*)(krow + 8);
        #pragma unroll
        for (int t = 0; t < 8; ++t)
            s += bs2f(q0[t])*bs2f(k0[t]) + bs2f(q1[t])*bs2f(k1[t]);
    }
    // full 64-dot: reduce over the 4 cooperating dsegs
    s += __shfl_xor(s, 16);
    s += __shfl_xor(s, 32);
    s = valid ? s * 0.125f : -1e30f;   // 1/sqrt(64)

    // softmax over the 16 slot lanes (invalid slots contribute 0)
    float m = s;
    #pragma unroll
    for (int off = 1; off < 16; off <<= 1) m = fmaxf(m, __shfl_xor(m, off));
    float p = valid ? __expf(s - m) : 0.f;
    float den = p;
    #pragma unroll
    for (int off = 1; off < 16; off <<= 1) den += __shfl_xor(den, off);
    p /= den;

    // PV: lane owns output dim d = lane; p/j broadcast as scalars
    float acc = 0.f;
    const bf16* vbase = v + (size_t)bb*SEQ*ED + hh*HD;
    #pragma unroll
    for (int sl = 0; sl < 13; ++sl) {
        const int js = __builtin_amdgcn_readlane(j, sl);
        if (js >= 0) {
            const float ps = __builtin_bit_cast(float,
                __builtin_amdgcn_readlane(__builtin_bit_cast(int, p), sl));
            acc += ps * b2f(vbase[(size_t)js*ED + lane]);
        }
    }
    out[((size_t)bb*SEQ + i)*ED + hh*HD + lane] = f2b(acc);
}

// ---------------------------------------------------------------------------
extern "C" void kernel_launch(void* const* d_in, const int* in_sizes, int n_in,
                              void* d_out, int out_size, void* d_ws, size_t ws_size,
                              hipStream_t stream) {
    const float* x   = (const float*)d_in[0];
    const float* qWv = (const float*)d_in[1];
    const float* qWr = (const float*)d_in[2];
    const float* qWl = (const float*)d_in[3];
    const float* qb  = (const float*)d_in[4];
    const float* kWv = (const float*)d_in[5];
    const float* kWr = (const float*)d_in[6];
    const float* kWl = (const float*)d_in[7];
    const float* kb  = (const float*)d_in[8];
    const float* vWv = (const float*)d_in[9];
    const float* vWr = (const float*)d_in[10];
    const float* vWl = (const float*)d_in[11];
    const float* vb  = (const float*)d_in[12];
    const float* oWv = (const float*)d_in[13];
    const float* oWr = (const float*)d_in[14];
    const float* oWl = (const float*)d_in[15];
    const float* ob  = (const float*)d_in[16];
    // d_in[17] = sparse_mask: structural, computed analytically in-kernel.

    const size_t QKV = (size_t)NROWS*ED;   // 6.29M elems
    bf16* xb  = (bf16*)d_ws;
    bf16* q   = xb + QKV;
    bf16* k   = q + QKV;
    bf16* v   = k + QKV;
    bf16* ao  = v + QKV;
    bf16* Wd  = ao + QKV;                  // 4 x ED*ED (q,k,v,o)
    bf16* Wdo = Wd + (size_t)3*ED*ED;
    // ws use: 5*12.58MB + 4*1.18MB ~= 67.6 MB

    xcvt<<<NROWS*ED/8/256, 256, 0, stream>>>(x, xb);
    densify4<<<dim3(ED*ED/256, 4), 256, 0, stream>>>(
        qWv,qWr,qWl, kWv,kWr,kWl, vWv,vWr,vWl, oWv,oWr,oWl, Wd);

    // fused q/k/v banded GEMM (z = projection; Wd and out z-strided)
    urdhva_gemm<4, true><<<dim3(NROWS/256, NB, 3), 256, 0, stream>>>(
        xb, Wd, qb, kb, vb, q);

    sparse_attn<<<(NBATCH*NH*SEQ)/4, 256, 0, stream>>>(q, k, v, ao);

    urdhva_gemm<2, false><<<dim3(NROWS/128, NB, 1), 256, 0, stream>>>(
        ao, Wdo, ob, ob, ob, d_out);
}

// Round 6
// 116.091 us; speedup vs baseline: 3.7381x; 1.2733x over previous
//
#include <hip/hip_runtime.h>
#include <hip/hip_bf16.h>

typedef __hip_bfloat16 bf16;
typedef __attribute__((ext_vector_type(8))) short short8;   // 8 bf16 in 4 VGPRs
typedef __attribute__((ext_vector_type(4))) float f32x4;

#define ED 768
#define NB 8
#define BS 96
#define NH 12
#define HD 64
#define SEQ 2048
#define NBATCH 4
#define NROWS (NBATCH*SEQ)   // 8192

__device__ __forceinline__ float b2f(bf16 v){ return __bfloat162float(v); }
__device__ __forceinline__ bf16 f2b(float v){ return __float2bfloat16(v); }
__device__ __forceinline__ short f2bs(float v){
    return (short)__builtin_bit_cast(unsigned short, __float2bfloat16(v));
}
__device__ __forceinline__ unsigned pkbf16(float lo, float hi){
    return (unsigned)(unsigned short)f2bs(lo) |
           ((unsigned)(unsigned short)f2bs(hi) << 16);
}

// ---------------------------------------------------------------------------
// One-time convert x (f32) -> bf16.
// ---------------------------------------------------------------------------
__global__ __launch_bounds__(256) void xcvt(
    const float* __restrict__ x, bf16* __restrict__ xb)
{
    const int idx = blockIdx.x*256 + threadIdx.x;     // one short8 per thread
    const float4 a = ((const float4*)x)[(size_t)idx*2];
    const float4 c = ((const float4*)x)[(size_t)idx*2 + 1];
    short8 o;
    o[0]=f2bs(a.x); o[1]=f2bs(a.y); o[2]=f2bs(a.z); o[3]=f2bs(a.w);
    o[4]=f2bs(c.x); o[5]=f2bs(c.y); o[6]=f2bs(c.z); o[7]=f2bs(c.w);
    ((short8*)xb)[idx] = o;
}

// ---------------------------------------------------------------------------
// Densify all 4 urdhva weight sets into Wd[z][t][s] (768x768 bf16 transposed).
// ---------------------------------------------------------------------------
__global__ __launch_bounds__(256) void densify4(
    const float* __restrict__ qWv, const float* __restrict__ qWr, const float* __restrict__ qWl,
    const float* __restrict__ kWv, const float* __restrict__ kWr, const float* __restrict__ kWl,
    const float* __restrict__ vWv, const float* __restrict__ vWr, const float* __restrict__ vWl,
    const float* __restrict__ oWv, const float* __restrict__ oWr, const float* __restrict__ oWl,
    bf16* __restrict__ WdBase)
{
    const int z = blockIdx.y;
    const float* Wv = (z==0)?qWv:(z==1)?kWv:(z==2)?vWv:oWv;
    const float* Wr = (z==0)?qWr:(z==1)?kWr:(z==2)?vWr:oWr;
    const float* Wl = (z==0)?qWl:(z==1)?kWl:(z==2)?vWl:oWl;
    bf16* Wd = WdBase + (size_t)z*ED*ED;

    const int idx = blockIdx.x*256 + threadIdx.x;   // over 768*768
    const int t = idx / ED, s = idx - t*ED;
    const int bt = t / BS, tt = t - bt*BS;
    const int bs = s / BS, ss = s - bs*BS;
    float val = 0.f;
    if (bs == bt)        val = Wv[(bt*BS + ss)*BS + tt];
    else if (bs == bt-1) val = Wr[((bt-1)*BS + ss)*BS + tt];
    else if (bs == bt+1) val = Wl[(bt*BS + ss)*BS + tt];
    Wd[idx] = f2b(val);
}

// ---------------------------------------------------------------------------
// Banded MFMA GEMM. z==2 (the v projection, OBF16 path) writes its output
// TRANSPOSED: vT[col][row] (row-major over rows), packing the 4 consecutive
// per-reg rows into one 8B store.
// ---------------------------------------------------------------------------
template<int RF, bool OBF16>
__global__ __launch_bounds__(256) void urdhva_gemm(
    const bf16* __restrict__ A,         // [NROWS][ED] bf16
    const bf16* __restrict__ WdBase,    // z-strided ED*ED
    const float* __restrict__ bias0, const float* __restrict__ bias1,
    const float* __restrict__ bias2,
    void* __restrict__ OutBase)         // z-strided NROWS*ED
{
    const int z = blockIdx.z;
    const bf16* Wd = WdBase + (size_t)z*ED*ED;
    const float* bias = (z==0) ? bias0 : (z==1) ? bias1 : bias2;

    const int lane = threadIdx.x & 63;
    const int wave = threadIdx.x >> 6;
    const int rowbase = blockIdx.x*(RF*64) + wave*(RF*16);
    const int ob = blockIdx.y;
    const int colbase = ob*BS;
    const int klo = (ob==0)    ? 0  : (ob-1)*BS;
    const int khi = (ob==NB-1) ? ED : (ob+2)*BS;

    const int l15 = lane & 15;
    const int lk8 = (lane >> 4) << 3;

    f32x4 acc[RF][6];
    #pragma unroll
    for (int i=0;i<RF;++i)
        #pragma unroll
        for (int j=0;j<6;++j) acc[i][j] = (f32x4){0.f,0.f,0.f,0.f};

    const bf16* abase = A  + (size_t)(rowbase + l15)*ED + lk8;
    const bf16* wbase = Wd + (size_t)(colbase + l15)*ED + lk8;

    for (int k0 = klo; k0 < khi; k0 += 32) {
        short8 a[RF], b[6];
        #pragma unroll
        for (int rf = 0; rf < RF; ++rf)
            a[rf] = *(const short8*)(abase + (size_t)rf*16*ED + k0);
        #pragma unroll
        for (int nf = 0; nf < 6; ++nf)
            b[nf] = *(const short8*)(wbase + (size_t)nf*16*ED + k0);
        #pragma unroll
        for (int rf = 0; rf < RF; ++rf)
            #pragma unroll
            for (int nf = 0; nf < 6; ++nf)
                acc[rf][nf] = __builtin_amdgcn_mfma_f32_16x16x32_bf16(
                                  a[rf], b[nf], acc[rf][nf], 0, 0, 0);
    }

    const int rbase = (lane >> 4) * 4;
    if (OBF16 && z == 2) {
        // transposed store: vT[col][row], 4 rows packed per 8B
        bf16* vT = (bf16*)OutBase + (size_t)2*NROWS*ED;
        #pragma unroll
        for (int rf = 0; rf < RF; ++rf) {
            #pragma unroll
            for (int nf = 0; nf < 6; ++nf) {
                const int col = colbase + nf*16 + l15;
                const float bv = bias[col];
                const int row0 = rowbase + rf*16 + rbase;
                uint2 dw;
                dw.x = pkbf16(acc[rf][nf][0] + bv, acc[rf][nf][1] + bv);
                dw.y = pkbf16(acc[rf][nf][2] + bv, acc[rf][nf][3] + bv);
                *(uint2*)(vT + (size_t)col*NROWS + row0) = dw;
            }
        }
    } else {
        #pragma unroll
        for (int rf = 0; rf < RF; ++rf) {
            #pragma unroll
            for (int nf = 0; nf < 6; ++nf) {
                const int col = colbase + nf*16 + l15;
                const float bv = bias[col];
                #pragma unroll
                for (int r = 0; r < 4; ++r) {
                    const int row = rowbase + rf*16 + rbase + r;
                    const float vv = acc[rf][nf][r] + bv;
                    if (OBF16)
                        ((bf16*)OutBase)[(size_t)z*NROWS*ED + (size_t)row*ED + col] = f2b(vv);
                    else
                        ((float*)OutBase)[(size_t)row*ED + col] = vv;
                }
            }
        }
    }
}

// ---------------------------------------------------------------------------
// MFMA sparse attention. One wave handles 16 consecutive queries [i0, i0+16)
// of one (batch, head). All valid keys fall in 8 aligned 16-key tiles at
// bases i0 - {0,16,32,64,128,256,512,1024}. S-tiles via mfma(K,Q) ->
// D[key][q] (q = lane&15, key = 4*(lane>>4)+reg), structural mask, softmax
// (mostly lane-local, 2 shfl_xor levels), P->bf16 in LDS [16][136] (padded,
// conflict-free b128), PV via mfma(P, vT) with vT[dim][row] layout.
// ---------------------------------------------------------------------------
__global__ __launch_bounds__(256) void sparse_attn_mfma(
    const bf16* __restrict__ q, const bf16* __restrict__ k,
    const bf16* __restrict__ vT, bf16* __restrict__ out)
{
    __shared__ __align__(16) unsigned short Plds[4][16][136];

    const int lane = threadIdx.x & 63;
    const int wid  = threadIdx.x >> 6;
    const int w  = blockIdx.x*4 + wid;        // 0 .. 6143
    const int qt = w & 127;
    const int hb = w >> 7;                    // 0..47
    const int h  = hb % NH;
    const int bb = hb / NH;
    const int i0 = qt << 4;

    const int l15 = lane & 15;
    const int g   = lane >> 4;

    // Q B-fragments (dims [g*8,+8) and +32)
    const bf16* qbase = q + ((size_t)bb*SEQ + i0 + l15)*ED + h*HD + g*8;
    const short8 qf0 = *(const short8*)qbase;
    const short8 qf1 = *(const short8*)(qbase + 32);

    int bases[8];
    bases[0]=i0;     bases[1]=i0-16;  bases[2]=i0-32;  bases[3]=i0-64;
    bases[4]=i0-128; bases[5]=i0-256; bases[6]=i0-512; bases[7]=i0-1024;

    const bf16* kbb = k + (size_t)bb*SEQ*ED + h*HD;

    float p[8][4];
    #pragma unroll
    for (int t = 0; t < 8; ++t) {
        f32x4 acc = (f32x4){0.f,0.f,0.f,0.f};
        if (bases[t] >= 0) {
            const bf16* kp = kbb + (size_t)(bases[t] + l15)*ED + g*8;
            const short8 kf0 = *(const short8*)kp;
            const short8 kf1 = *(const short8*)(kp + 32);
            acc = __builtin_amdgcn_mfma_f32_16x16x32_bf16(kf0, qf0, acc, 0,0,0);
            acc = __builtin_amdgcn_mfma_f32_16x16x32_bf16(kf1, qf1, acc, 0,0,0);
        }
        const int Dt = i0 - bases[t];
        #pragma unroll
        for (int r = 0; r < 4; ++r) {
            // element: query = i0 + l15, key = bases[t] + 4g + r
            const int delta = Dt + l15 - 4*g - r;
            const bool val = (bases[t] >= 0) &&
                (((unsigned)delta <= 4u) ||
                 (delta >= 8 && (delta & (delta-1)) == 0));
            p[t][r] = val ? acc[r]*0.125f : -1e30f;   // 1/sqrt(64)
        }
    }

    // softmax over 128 keys per query: 32 local values + xor16/xor32
    float m = -1e30f;
    #pragma unroll
    for (int t = 0; t < 8; ++t)
        #pragma unroll
        for (int r = 0; r < 4; ++r) m = fmaxf(m, p[t][r]);
    m = fmaxf(m, __shfl_xor(m, 16));
    m = fmaxf(m, __shfl_xor(m, 32));

    float den = 0.f;
    #pragma unroll
    for (int t = 0; t < 8; ++t)
        #pragma unroll
        for (int r = 0; r < 4; ++r) { p[t][r] = __expf(p[t][r] - m); den += p[t][r]; }
    den += __shfl_xor(den, 16);
    den += __shfl_xor(den, 32);
    const float inv = 1.f / den;

    // write P (bf16) to LDS: row q = l15 (136-elem padded row), key = 16t+4g+{0..3}
    {
        char* prow = (char*)&Plds[wid][l15][0];
        #pragma unroll
        for (int t = 0; t < 8; ++t) {
            *(unsigned*)(prow + 32*t + 8*g)     = pkbf16(p[t][0]*inv, p[t][1]*inv);
            *(unsigned*)(prow + 32*t + 8*g + 4) = pkbf16(p[t][2]*inv, p[t][3]*inv);
        }
    }

    // PV: O[q][d] = sum_key P[q][key] * V[key][d], 4 key-chunks x 4 dim-tiles
    f32x4 accO[4];
    #pragma unroll
    for (int nt = 0; nt < 4; ++nt) accO[nt] = (f32x4){0.f,0.f,0.f,0.f};

    const bf16* vbb = vT + (size_t)bb*SEQ;    // + col*NROWS later
    #pragma unroll
    for (int u = 0; u < 4; ++u) {
        if (bases[2*u] < 0 && bases[2*u+1] < 0) continue;   // uniform skip
        const short8 pa = *(const short8*)((char*)&Plds[wid][l15][0] + 64*u + 16*g);
        const int tb  = (g & 2) ? bases[2*u+1] : bases[2*u];
        const int tbc = (tb < 0 ? 0 : tb) + 8*(g & 1);      // P is 0 where tb<0
        #pragma unroll
        for (int nt = 0; nt < 4; ++nt) {
            const short8 vb = *(const short8*)(vbb +
                (size_t)(h*HD + 16*nt + l15)*NROWS + tbc);
            accO[nt] = __builtin_amdgcn_mfma_f32_16x16x32_bf16(pa, vb, accO[nt], 0,0,0);
        }
    }

    // store: D row = q-offset 4g+r, col = dim 16nt+l15
    #pragma unroll
    for (int nt = 0; nt < 4; ++nt)
        #pragma unroll
        for (int r = 0; r < 4; ++r)
            out[((size_t)bb*SEQ + i0 + 4*g + r)*ED + h*HD + 16*nt + l15] =
                f2b(accO[nt][r]);
}

// ---------------------------------------------------------------------------
extern "C" void kernel_launch(void* const* d_in, const int* in_sizes, int n_in,
                              void* d_out, int out_size, void* d_ws, size_t ws_size,
                              hipStream_t stream) {
    const float* x   = (const float*)d_in[0];
    const float* qWv = (const float*)d_in[1];
    const float* qWr = (const float*)d_in[2];
    const float* qWl = (const float*)d_in[3];
    const float* qb  = (const float*)d_in[4];
    const float* kWv = (const float*)d_in[5];
    const float* kWr = (const float*)d_in[6];
    const float* kWl = (const float*)d_in[7];
    const float* kb  = (const float*)d_in[8];
    const float* vWv = (const float*)d_in[9];
    const float* vWr = (const float*)d_in[10];
    const float* vWl = (const float*)d_in[11];
    const float* vb  = (const float*)d_in[12];
    const float* oWv = (const float*)d_in[13];
    const float* oWr = (const float*)d_in[14];
    const float* oWl = (const float*)d_in[15];
    const float* ob  = (const float*)d_in[16];
    // d_in[17] = sparse_mask: structural, computed analytically in-kernel.

    const size_t QKV = (size_t)NROWS*ED;   // 6.29M elems
    bf16* xb  = (bf16*)d_ws;
    bf16* q   = xb + QKV;
    bf16* k   = q + QKV;
    bf16* vT  = k + QKV;                   // v, stored transposed [col][row]
    bf16* ao  = vT + QKV;
    bf16* Wd  = ao + QKV;                  // 4 x ED*ED (q,k,v,o)
    bf16* Wdo = Wd + (size_t)3*ED*ED;

    xcvt<<<NROWS*ED/8/256, 256, 0, stream>>>(x, xb);
    densify4<<<dim3(ED*ED/256, 4), 256, 0, stream>>>(
        qWv,qWr,qWl, kWv,kWr,kWl, vWv,vWr,vWl, oWv,oWr,oWl, Wd);

    // fused q/k/v banded GEMM; z==2 writes vT transposed
    urdhva_gemm<4, true><<<dim3(NROWS/256, NB, 3), 256, 0, stream>>>(
        xb, Wd, qb, kb, vb, q);

    sparse_attn_mfma<<<(NBATCH*NH*(SEQ/16))/4, 256, 0, stream>>>(q, k, vT, ao);

    urdhva_gemm<2, false><<<dim3(NROWS/128, NB, 1), 256, 0, stream>>>(
        ao, Wdo, ob, ob, ob, d_out);
}